// Round 12
// baseline (57.004 us; speedup 1.0000x reference)
//
#include <hip/hip_runtime.h>

// Problem constants
#define LSEQ 1024
#define NBATCH 2
#define NH 16
#define HDIM 64
#define WWIN 64
#define M_GEMM 2048   // NBATCH*LSEQ
#define K_GEMM 1024
#define N_GEMM 1024
#define PLANE_ELEMS (1u << 21)   // u16 per [B,H,L,64] plane (4 MB)

#define BKT 64        // GEMM K-step

typedef __bf16 bf16x8 __attribute__((ext_vector_type(8)));
typedef _Float16 f16x8 __attribute__((ext_vector_type(8)));
typedef float f32x4 __attribute__((ext_vector_type(4)));

typedef __attribute__((address_space(1))) const unsigned int gas_uint;
typedef __attribute__((address_space(3))) unsigned int las_uint;

__device__ __forceinline__ unsigned short f2bf(float f) {
  unsigned int u = __float_as_uint(f);
  u += 0x7fff + ((u >> 16) & 1);   // round-to-nearest-even
  return (unsigned short)(u >> 16);
}
__device__ __forceinline__ unsigned short f2h(float f) {
  const _Float16 h = (_Float16)f;  // v_cvt_f16_f32, RTNE
  return __builtin_bit_cast(unsigned short, h);
}

union F16_8 { f16x8 v; unsigned short u[8]; };

// ---- fused pre-pass: x cast (0..2047), trig (2048..2175), W^T (2176..6271),
// ---- zero-pad page (6272)
__global__ void prep_all_k(const float* __restrict__ x,
                           unsigned short* __restrict__ xb,
                           const float* __restrict__ freqs,
                           float* __restrict__ ctab, float* __restrict__ stab,
                           const float* __restrict__ W0,
                           const float* __restrict__ W1,
                           const float* __restrict__ W2,
                           const float* __restrict__ W3,
                           unsigned short* __restrict__ Wt,
                           unsigned short* __restrict__ zp) {
  __shared__ float tile[32][33];
  const int bid = blockIdx.x;
  const int tid = threadIdx.x;
  if (bid < 2048) {
    const int i = bid * 256 + tid;
    const float4 v = reinterpret_cast<const float4*>(x)[i];
    ushort4 o;
    o.x = f2bf(v.x); o.y = f2bf(v.y); o.z = f2bf(v.z); o.w = f2bf(v.w);
    reinterpret_cast<ushort4*>(xb)[i] = o;
  } else if (bid < 2176) {
    const int i = (bid - 2048) * 256 + tid;  // 0..32767
    float s, c;
    sincosf(freqs[i], &s, &c);
    ctab[i] = c;
    stab[i] = s;
  } else if (bid < 6272) {
    const int t = bid - 2176;
    const int z = t >> 10;
    const float* src = (z == 0) ? W0 : (z == 1) ? W1 : (z == 2) ? W2 : W3;
    unsigned short* dst = Wt + ((size_t)z << 20);
    const int rem = t & 1023;
    const int n0 = (rem & 31) << 5, k0 = (rem >> 5) << 5;
    const int tx = tid & 31, ty = tid >> 5;   // 32 x 8
#pragma unroll
    for (int i = 0; i < 32; i += 8)
      tile[ty + i][tx] = src[(size_t)(k0 + ty + i) * 1024 + n0 + tx];
    __syncthreads();
#pragma unroll
    for (int i = 0; i < 32; i += 8)
      dst[(size_t)(n0 + ty + i) * 1024 + k0 + tx] = f2bf(tile[tx][ty + i]);
  } else {
    ushort4 zz = {0, 0, 0, 0};
    reinterpret_cast<ushort4*>(zp)[tid] = zz;   // 4 KB of zeros
  }
}

// ---------------- GEMM: C = A(MxK) * B(KxN), A bf16 row-major, Bt = B^T (NxK) bf16
// BK=64, double-buffered 2-phase, chunk-XOR swizzle (linear LDS dest +
// pre-swizzled global source + swizzled fragment read), XCD-swizzled grid.
// Waves arranged WM x WN over the tile (wave tile (TBM/WM) x (TBN/WN)) --
// WM=2 halves the per-wave A-frag reads vs WM=1 at identical occupancy,
// cutting CU-level LDS issue traffic 20% (the measured ~58%-efficiency
// bottleneck), with accumulation order per output element unchanged.
// MODE 0: 512-thr/8-wave (2x4). RoPE (z<2) fused; fp16 planes out, u32-packed
//         pair stores. MODE 1: 256-thr/4-wave (2x2), fp32 row-major out.
__device__ __forceinline__ void gload16(const void* g, void* l) {
  __builtin_amdgcn_global_load_lds((gas_uint*)g, (las_uint*)l, 16, 0, 0);
}

template <int MODE, int TBM, int TBN, int WM, int WN, int THREADS>
__global__ __launch_bounds__(THREADS, (THREADS == 512) ? 6 : 3) void gemm_bf16_k(
    const unsigned short* __restrict__ A,
    const unsigned short* __restrict__ Bt0,
    void* __restrict__ C0,
    const float* __restrict__ ctab,
    const float* __restrict__ stab) {
  constexpr int NBM = M_GEMM / TBM;
  constexpr int NBN = N_GEMM / TBN;
  constexpr int NZ = (MODE == 0) ? 3 : 1;
  constexpr int RW = TBM / WM;               // wave row span
  constexpr int CW = TBN / WN;               // wave col span (>=16)
  constexpr int MI = RW / 16;                // A frags per wave
  constexpr int NJ = CW / 16;                // B frags per wave
  constexpr int ASZ = TBM * BKT;             // elements per A buffer
  constexpr int BSZ = TBN * BKT;
  constexpr int RND = THREADS * 8;           // elems staged per slab-round
  constexpr int ASL = ASZ / RND;
  constexpr int BSL = BSZ / RND;
  constexpr int NT = K_GEMM / BKT;           // 16 K-steps
  constexpr int CPX = NBM * NBN * NZ / 8;    // blocks per XCD
  __shared__ unsigned short sA[2 * ASZ];
  __shared__ unsigned short sB[2 * BSZ];

  const int tid = threadIdx.x;
  const int lane = tid & 63;
  const int wave = tid >> 6;
  const int wm = wave / WN;
  const int wn = wave % WN;

  // XCD-aware decode (bijective: grid % 8 == 0)
  const int p = blockIdx.x;
  const int lid = (p & 7) * CPX + (p >> 3);
  const int z = lid / (NBM * NBN);
  const int rem = lid % (NBM * NBN);
  const int bm = rem % NBM;
  const int bn = rem / NBM;

  const unsigned short* Bt = Bt0 + (size_t)z * ((size_t)N_GEMM * K_GEMM);
  const int m0 = bm * TBM, n0 = bn * TBN;

  // staging: item = slab*THREADS + tid -> row = slab*(THREADS/8) + tid>>3,
  // chunk = tid&7; source k-chunk swizzled: phys = chunk ^ (row&7).
  const int skoff = (((tid & 7) ^ ((tid >> 3) & 7)) << 3);   // element offset

  const unsigned short* gA[ASL];
  const unsigned short* gB[BSL];
#pragma unroll
  for (int s = 0; s < ASL; ++s)
    gA[s] = A + (size_t)(m0 + s * (THREADS / 8) + (tid >> 3)) * K_GEMM + skoff;
#pragma unroll
  for (int s = 0; s < BSL; ++s)
    gB[s] = Bt + (size_t)(n0 + s * (THREADS / 8) + (tid >> 3)) * K_GEMM + skoff;

  f32x4 acc[MI][NJ] = {};

  const int fr = lane & 15;
  const int lg = lane >> 4;
  // fragment read: chunk c = ks*4+lg, phys = c ^ (fr&7); co1 = co0 ^ 32 elems
  const int co0 = ((lg ^ (fr & 7)) << 3);
  const int co1 = co0 ^ 32;

  // prologue: stage tile 0 into buffer 0
#pragma unroll
  for (int s = 0; s < ASL; ++s) gload16(gA[s], sA + (s * THREADS + tid) * 8);
#pragma unroll
  for (int s = 0; s < BSL; ++s) gload16(gB[s], sB + (s * THREADS + tid) * 8);
  __syncthreads();

#pragma unroll 2
  for (int t = 0; t < NT; ++t) {
    const int cur = t & 1;
    const int nxt = cur ^ 1;
    if (t + 1 < NT) {                 // stage next tile early (overlaps compute)
      const int kt = (t + 1) * BKT;
#pragma unroll
      for (int s = 0; s < ASL; ++s)
        gload16(gA[s] + kt, sA + nxt * ASZ + (s * THREADS + tid) * 8);
#pragma unroll
      for (int s = 0; s < BSL; ++s)
        gload16(gB[s] + kt, sB + nxt * BSZ + (s * THREADS + tid) * 8);
    }
    const unsigned short* cA = sA + cur * ASZ;
    const unsigned short* cB = sB + cur * BSZ;
    bf16x8 af[2][MI], bfr[2][NJ];
#pragma unroll
    for (int i = 0; i < MI; i++) {
      af[0][i] = *reinterpret_cast<const bf16x8*>(&cA[(wm * RW + i * 16 + fr) * BKT + co0]);
      af[1][i] = *reinterpret_cast<const bf16x8*>(&cA[(wm * RW + i * 16 + fr) * BKT + co1]);
    }
#pragma unroll
    for (int j = 0; j < NJ; j++) {
      bfr[0][j] = *reinterpret_cast<const bf16x8*>(&cB[(wn * CW + j * 16 + fr) * BKT + co0]);
      bfr[1][j] = *reinterpret_cast<const bf16x8*>(&cB[(wn * CW + j * 16 + fr) * BKT + co1]);
    }
#pragma unroll
    for (int ks = 0; ks < 2; ks++)
#pragma unroll
      for (int i = 0; i < MI; i++)
#pragma unroll
        for (int j = 0; j < NJ; j++)
          acc[i][j] = __builtin_amdgcn_mfma_f32_16x16x32_bf16(af[ks][i], bfr[ks][j], acc[i][j], 0, 0, 0);
    __syncthreads();
  }

  const int fq = lane >> 4;
  const bool dorope = (MODE == 0) && (z < 2);
#pragma unroll
  for (int i = 0; i < MI; i++) {
#pragma unroll
    for (int j = 0; j < NJ; j++) {
#pragma unroll
      for (int r = 0; r < 4; r++) {
        const int row = m0 + wm * RW + i * 16 + fq * 4 + r;
        const int col = n0 + wn * CW + j * 16 + fr;
        float v = acc[i][j][r];
        if (MODE == 0) {
          const int l = row & 1023, d = col & 63;
          if (dorope) {
            // pair partner (d^1) lives in lane^1 (same i,j,r)
            const float other = __shfl_xor(v, 1);
            const int ti = (l << 5) + (d >> 1);
            const float c = ctab[ti], s = stab[ti];
            v = (d & 1) ? (other * s + v * c) : (v * c - other * s);
          }
          if (z == 0) v *= 0.125f;               // fold attn scale into Q
          // packed pair store: even-fr lane stores (own, partner) as u32
          const float vp = __shfl_xor(v, 1);
          if (!(fr & 1)) {
            const int b = row >> 10, h = col >> 6;
            const size_t idx = ((((size_t)b * NH + h) * LSEQ + l) << 6) + d;
            const unsigned int pk = (unsigned)f2h(v) | ((unsigned)f2h(vp) << 16);
            ((unsigned int*)C0)[((size_t)z * PLANE_ELEMS + idx) >> 1] = pk;
          }
        } else {
          ((float*)C0)[(size_t)row * N_GEMM + col] = v;
        }
      }
    }
  }
}

// ---------------- local windowed attention v5 (fp16 MFMA) -----------------
// Block = (bh, 64-query tile), XCD-swizzled grid. K span rows j=0..127 map to
// key l = lb-64+j (zero page for l<0 -> reference zero-pad softmax exactly).
// KF plane DMA'd via global_load_lds with pre-swizzled per-lane source.
// Q frags loaded directly as f16x8 (plane already scaled). P,V fp16.
__device__ __forceinline__ int kaddr(int j, int d) {   // Ks: 128 rows x 128B
  return j * 128 + ((((d >> 3) ^ (j & 7)) & 7) << 4) + ((d & 7) << 1);
}
__device__ __forceinline__ int taddr(int r, int c) {   // Vt/Ps: 64 rows x 256B
  return r * 256 + ((((c >> 3) ^ (r & 7)) & 15) << 4) + ((c & 7) << 1);
}

__global__ __launch_bounds__(256, 2) void local_attn5_k(
    const unsigned short* __restrict__ planes,
    const unsigned short* __restrict__ zp,
    unsigned short* __restrict__ O) {
  __shared__ __align__(16) unsigned char KsF[16384];
  __shared__ __align__(16) unsigned char VtB[16384];
  __shared__ __align__(16) unsigned char PsB[16384];

  const int tid = threadIdx.x;
  const int lane = tid & 63;
  const int wave = tid >> 6;
  const int lr = lane & 15;
  const int lg = lane >> 4;
  const int pb = blockIdx.x;
  const int lid = (pb & 7) * 64 + (pb >> 3);   // 512 = 8*64; bh-major per XCD
  const int bh = lid >> 4;
  const int lb = (lid & 15) << 6;

  const unsigned short* QFb = planes + ((size_t)bh << 16);
  const unsigned short* KFb = planes + (size_t)PLANE_ELEMS + ((size_t)bh << 16);
  const unsigned short* VFb = planes + 2 * (size_t)PLANE_ELEMS + ((size_t)bh << 16);

  // ---- K staging: pure DMA, source pre-swizzled to match kaddr ----
#pragma unroll
  for (int r = 0; r < 4; ++r) {
    const int item = r * 256 + tid;       // 0..1023
    const int j = item >> 3;              // 0..127
    const int c = item & 7;               // 16B chunk
    const int g = lb - 64 + j;
    const int sc = ((c ^ (j & 7)) << 3);  // swizzled source chunk (elements)
    const unsigned short* sK = (g >= 0) ? KFb + ((size_t)g << 6) + sc : zp + (c << 3);
    gload16(sK, KsF + item * 16);
  }

  // ---- V transpose staging from fp16 plane (bit-level pack, no math) ----
#pragma unroll
  for (int pp = 0; pp < 4; ++pp) {
    const int item = pp * 256 + tid;      // 0..1023
    const int jp = item >> 4;             // 0..63 (pair of j)
    const int d0 = (item & 15) << 2;      // 0..60
    const int g0 = lb - 64 + 2 * jp;
    ushort4 a = {0, 0, 0, 0}, b = {0, 0, 0, 0};
    if (g0 >= 0) a = *reinterpret_cast<const ushort4*>(VFb + ((size_t)g0 << 6) + d0);
    if (g0 + 1 >= 0) b = *reinterpret_cast<const ushort4*>(VFb + ((size_t)(g0 + 1) << 6) + d0);
    *reinterpret_cast<unsigned int*>(VtB + taddr(d0 + 0, 2 * jp)) = (unsigned)a.x | ((unsigned)b.x << 16);
    *reinterpret_cast<unsigned int*>(VtB + taddr(d0 + 1, 2 * jp)) = (unsigned)a.y | ((unsigned)b.y << 16);
    *reinterpret_cast<unsigned int*>(VtB + taddr(d0 + 2, 2 * jp)) = (unsigned)a.z | ((unsigned)b.z << 16);
    *reinterpret_cast<unsigned int*>(VtB + taddr(d0 + 3, 2 * jp)) = (unsigned)a.w | ((unsigned)b.w << 16);
  }
  __syncthreads();   // drains gload16 vmcnt + ds_writes

  // ---- Q fragments: direct f16x8 loads (plane already scaled by 0.125) ----
  const int rtbase = wave * 16;
  const size_t qoff = ((size_t)(lb + rtbase + lr) << 6);
  F16_8 qf[2];
#pragma unroll
  for (int ks = 0; ks < 2; ++ks)
    qf[ks].v = *reinterpret_cast<const f16x8*>(QFb + qoff + ks * 32 + lg * 8);

  // ---- scores: S[rt][j], wave owns rows rtbase..rtbase+15, all 128 j ----
  f32x4 acc[8] = {};
#pragma unroll
  for (int ks = 0; ks < 2; ++ks) {
    const int d0 = ks * 32 + lg * 8;
#pragma unroll
    for (int nt = 0; nt < 8; ++nt) {
      const int j = nt * 16 + lr;
      const f16x8 kf = *reinterpret_cast<const f16x8*>(KsF + kaddr(j, d0));
      acc[nt] = __builtin_amdgcn_mfma_f32_16x16x32_f16(qf[ks].v, kf, acc[nt], 0, 0, 0);
    }
  }

  // ---- masked softmax per row ----
  float sum4[4];
#pragma unroll
  for (int reg = 0; reg < 4; ++reg) {
    const int rt = rtbase + lg * 4 + reg;
    float m = -3.0e38f;
#pragma unroll
    for (int nt = 0; nt < 8; ++nt) {
      const int j = nt * 16 + lr;
      const bool valid = (j > rt) && (j <= rt + 64);
      const float sv = valid ? acc[nt][reg] : -3.0e38f;
      acc[nt][reg] = sv;
      m = fmaxf(m, sv);
    }
    m = fmaxf(m, __shfl_xor(m, 1));
    m = fmaxf(m, __shfl_xor(m, 2));
    m = fmaxf(m, __shfl_xor(m, 4));
    m = fmaxf(m, __shfl_xor(m, 8));
    float s = 0.f;
#pragma unroll
    for (int nt = 0; nt < 8; ++nt) {
      const float pv = (acc[nt][reg] > -1.0e37f) ? __expf(acc[nt][reg] - m) : 0.f;
      acc[nt][reg] = pv;
      s += pv;
    }
    s += __shfl_xor(s, 1);
    s += __shfl_xor(s, 2);
    s += __shfl_xor(s, 4);
    s += __shfl_xor(s, 8);
    sum4[reg] = s;
  }

  // ---- write P (fp16, swizzled; wave-private rows) ----
#pragma unroll
  for (int nt = 0; nt < 8; ++nt)
#pragma unroll
    for (int reg = 0; reg < 4; ++reg) {
      const int rt = rtbase + lg * 4 + reg;
      const int j = nt * 16 + lr;
      *reinterpret_cast<unsigned short*>(PsB + taddr(rt, j)) = f2h(acc[nt][reg]);
    }

  // ---- PV: out[rt][d] = sum_j P[rt][j] * V[j][d] ----
  f32x4 oacc[4] = {};
#pragma unroll
  for (int ks = 0; ks < 4; ++ks) {
    const int j0 = ks * 32 + lg * 8;
    const f16x8 pa = *reinterpret_cast<const f16x8*>(PsB + taddr(rtbase + lr, j0));
#pragma unroll
    for (int nt = 0; nt < 4; ++nt) {
      const int d = nt * 16 + lr;
      const f16x8 vf = *reinterpret_cast<const f16x8*>(VtB + taddr(d, j0));
      oacc[nt] = __builtin_amdgcn_mfma_f32_16x16x32_f16(pa, vf, oacc[nt], 0, 0, 0);
    }
  }

  // ---- normalize + write out (bf16, [b][l][h*64+d]) ----
  const int b = bh >> 4, h = bh & 15;
#pragma unroll
  for (int nt = 0; nt < 4; ++nt)
#pragma unroll
    for (int reg = 0; reg < 4; ++reg) {
      const int rt = rtbase + lg * 4 + reg;
      const int d = nt * 16 + lr;
      const float o = oacc[nt][reg] / sum4[reg];
      const int lq = lb + rt;
      O[(((size_t)b * LSEQ + lq) << 10) + (h << 6) + d] = f2bf(o);
    }
}

// ---------------- launch ----------------
extern "C" void kernel_launch(void* const* d_in, const int* in_sizes, int n_in,
                              void* d_out, int out_size, void* d_ws, size_t ws_size,
                              hipStream_t stream) {
  const float* x     = (const float*)d_in[0];
  const float* freqs = (const float*)d_in[1];
  const float* Wq    = (const float*)d_in[2];
  const float* Wk    = (const float*)d_in[3];
  const float* Wv    = (const float*)d_in[4];
  const float* Wo    = (const float*)d_in[5];
  float* out = (float*)d_out;
  char* ws = (char*)d_ws;

  // workspace layout (<= 28.8 MB)
  unsigned short* xb     = (unsigned short*)ws;                 // 4 MB: x bf16
  unsigned short* Wt     = (unsigned short*)(ws + (4u << 20));  // 8 MB: W^T bf16 x4
  unsigned short* planes = (unsigned short*)(ws + (12u << 20)); // 12 MB: QF KF VF (fp16)
  unsigned short* Oat    = (unsigned short*)(ws + (24u << 20)); // 4 MB: attn out bf16
  float* ctab = (float*)(ws + (28u << 20));                     // 128 KB
  float* stab = ctab + 32768;                                   // 128 KB
  unsigned short* zp = (unsigned short*)(ws + (28u << 20) + (1u << 19)); // 4 KB zeros

  prep_all_k<<<6273, 256, 0, stream>>>(x, xb, freqs, ctab, stab, Wq, Wk, Wv, Wo, Wt, zp);

  // Q,K,V = x @ {Wq,Wk,Wv}: RoPE fused, fp16 planes out, packed stores
  // 64x128 tiles, BK=64, 8 waves as 2(m)x4(n) -> wave 32x32 (MI=NJ=2):
  // 20% fewer LDS frag reads/CU than 1x8 at the same 768-block/3-per-CU grid
  gemm_bf16_k<0, 64, 128, 2, 4, 512><<<768, 512, 0, stream>>>(xb, Wt, planes, ctab, stab);

  // local attention (fp16 MFMA) -> bf16 [B*L][D_MODEL]
  local_attn5_k<<<512, 256, 0, stream>>>(planes, zp, Oat);

  // final projection -> fp32 d_out (64x64 tiles, 4 waves as 2x2)
  gemm_bf16_k<1, 64, 64, 2, 2, 256><<<512, 256, 0, stream>>>(Oat, Wt + (3u << 20), out, ctab, stab);
}

// Round 13
// 54.173 us; speedup vs baseline: 1.0523x; 1.0523x over previous
//
#include <hip/hip_runtime.h>

// Problem constants
#define LSEQ 1024
#define NBATCH 2
#define NH 16
#define HDIM 64
#define WWIN 64
#define M_GEMM 2048   // NBATCH*LSEQ
#define K_GEMM 1024
#define N_GEMM 1024
#define PLANE_ELEMS (1u << 21)   // u16 per [B,H,L,64] plane (4 MB)

#define BKT 64        // GEMM K-step

typedef __bf16 bf16x8 __attribute__((ext_vector_type(8)));
typedef _Float16 f16x8 __attribute__((ext_vector_type(8)));
typedef float f32x4 __attribute__((ext_vector_type(4)));

typedef __attribute__((address_space(1))) const unsigned int gas_uint;
typedef __attribute__((address_space(3))) unsigned int las_uint;

__device__ __forceinline__ unsigned short f2bf(float f) {
  unsigned int u = __float_as_uint(f);
  u += 0x7fff + ((u >> 16) & 1);   // round-to-nearest-even
  return (unsigned short)(u >> 16);
}
__device__ __forceinline__ unsigned short f2h(float f) {
  const _Float16 h = (_Float16)f;  // v_cvt_f16_f32, RTNE
  return __builtin_bit_cast(unsigned short, h);
}

union F16_8 { f16x8 v; unsigned short u[8]; };

// ---- fused pre-pass: x cast (0..2047), trig (2048..2175), W^T (2176..6271),
// ---- zero-pad page (6272)
__global__ void prep_all_k(const float* __restrict__ x,
                           unsigned short* __restrict__ xb,
                           const float* __restrict__ freqs,
                           float* __restrict__ ctab, float* __restrict__ stab,
                           const float* __restrict__ W0,
                           const float* __restrict__ W1,
                           const float* __restrict__ W2,
                           const float* __restrict__ W3,
                           unsigned short* __restrict__ Wt,
                           unsigned short* __restrict__ zp) {
  __shared__ float tile[32][33];
  const int bid = blockIdx.x;
  const int tid = threadIdx.x;
  if (bid < 2048) {
    const int i = bid * 256 + tid;
    const float4 v = reinterpret_cast<const float4*>(x)[i];
    ushort4 o;
    o.x = f2bf(v.x); o.y = f2bf(v.y); o.z = f2bf(v.z); o.w = f2bf(v.w);
    reinterpret_cast<ushort4*>(xb)[i] = o;
  } else if (bid < 2176) {
    const int i = (bid - 2048) * 256 + tid;  // 0..32767
    float s, c;
    sincosf(freqs[i], &s, &c);
    ctab[i] = c;
    stab[i] = s;
  } else if (bid < 6272) {
    const int t = bid - 2176;
    const int z = t >> 10;
    const float* src = (z == 0) ? W0 : (z == 1) ? W1 : (z == 2) ? W2 : W3;
    unsigned short* dst = Wt + ((size_t)z << 20);
    const int rem = t & 1023;
    const int n0 = (rem & 31) << 5, k0 = (rem >> 5) << 5;
    const int tx = tid & 31, ty = tid >> 5;   // 32 x 8
#pragma unroll
    for (int i = 0; i < 32; i += 8)
      tile[ty + i][tx] = src[(size_t)(k0 + ty + i) * 1024 + n0 + tx];
    __syncthreads();
#pragma unroll
    for (int i = 0; i < 32; i += 8)
      dst[(size_t)(n0 + ty + i) * 1024 + k0 + tx] = f2bf(tile[tx][ty + i]);
  } else {
    ushort4 zz = {0, 0, 0, 0};
    reinterpret_cast<ushort4*>(zp)[tid] = zz;   // 4 KB of zeros
  }
}

// ---------------- GEMM: C = A(MxK) * B(KxN), A bf16 row-major, Bt = B^T (NxK) bf16
// BK=64, double-buffered 2-phase, chunk-XOR swizzle (linear LDS dest +
// pre-swizzled global source + swizzled fragment read), XCD-swizzled grid.
// WM=1 wave layout (validated R7-R10; the R11 2x4 experiment regressed).
// MODE 0: 512-thr/8-wave (1x8), 64x128 tile, 768 blocks = 3/CU = 24 waves/CU.
//         RoPE (z<2) fused; fp16 planes out, u32-packed pair stores.
// MODE 1: 256-thr/4-wave (1x4), 32x64 tile, 1024 blocks = 4/CU = 16 waves/CU.
__device__ __forceinline__ void gload16(const void* g, void* l) {
  __builtin_amdgcn_global_load_lds((gas_uint*)g, (las_uint*)l, 16, 0, 0);
}

template <int MODE, int TBM, int TBN, int WN, int THREADS>
__global__ __launch_bounds__(THREADS, (THREADS == 512) ? 6 : 4) void gemm_bf16_k(
    const unsigned short* __restrict__ A,
    const unsigned short* __restrict__ Bt0,
    void* __restrict__ C0,
    const float* __restrict__ ctab,
    const float* __restrict__ stab) {
  constexpr int NBM = M_GEMM / TBM;
  constexpr int NBN = N_GEMM / TBN;
  constexpr int NZ = (MODE == 0) ? 3 : 1;
  constexpr int CW = TBN / WN;               // wave col span (>=16)
  constexpr int NJ = CW / 16;                // B frags per wave
  constexpr int MI = TBM / 16;               // A frags per wave (WM=1)
  constexpr int ASZ = TBM * BKT;             // elements per A buffer
  constexpr int BSZ = TBN * BKT;
  constexpr int RND = THREADS * 8;           // elems staged per slab-round
  constexpr int ASL = ASZ / RND;
  constexpr int BSL = BSZ / RND;
  constexpr int NT = K_GEMM / BKT;           // 16 K-steps
  constexpr int CPX = NBM * NBN * NZ / 8;    // blocks per XCD
  __shared__ unsigned short sA[2 * ASZ];
  __shared__ unsigned short sB[2 * BSZ];

  const int tid = threadIdx.x;
  const int lane = tid & 63;
  const int wave = tid >> 6;
  const int wn = wave;                 // WM=1

  // XCD-aware decode (bijective: grid % 8 == 0)
  const int p = blockIdx.x;
  const int lid = (p & 7) * CPX + (p >> 3);
  const int z = lid / (NBM * NBN);
  const int rem = lid % (NBM * NBN);
  const int bm = rem % NBM;
  const int bn = rem / NBM;

  const unsigned short* Bt = Bt0 + (size_t)z * ((size_t)N_GEMM * K_GEMM);
  const int m0 = bm * TBM, n0 = bn * TBN;

  // staging: item = slab*THREADS + tid -> row = slab*(THREADS/8) + tid>>3,
  // chunk = tid&7; source k-chunk swizzled: phys = chunk ^ (row&7).
  const int skoff = (((tid & 7) ^ ((tid >> 3) & 7)) << 3);   // element offset

  const unsigned short* gA[ASL];
  const unsigned short* gB[BSL];
#pragma unroll
  for (int s = 0; s < ASL; ++s)
    gA[s] = A + (size_t)(m0 + s * (THREADS / 8) + (tid >> 3)) * K_GEMM + skoff;
#pragma unroll
  for (int s = 0; s < BSL; ++s)
    gB[s] = Bt + (size_t)(n0 + s * (THREADS / 8) + (tid >> 3)) * K_GEMM + skoff;

  f32x4 acc[MI][NJ] = {};

  const int fr = lane & 15;
  const int lg = lane >> 4;
  // fragment read: chunk c = ks*4+lg, phys = c ^ (fr&7); co1 = co0 ^ 32 elems
  const int co0 = ((lg ^ (fr & 7)) << 3);
  const int co1 = co0 ^ 32;

  // prologue: stage tile 0 into buffer 0
#pragma unroll
  for (int s = 0; s < ASL; ++s) gload16(gA[s], sA + (s * THREADS + tid) * 8);
#pragma unroll
  for (int s = 0; s < BSL; ++s) gload16(gB[s], sB + (s * THREADS + tid) * 8);
  __syncthreads();

#pragma unroll 2
  for (int t = 0; t < NT; ++t) {
    const int cur = t & 1;
    const int nxt = cur ^ 1;
    if (t + 1 < NT) {                 // stage next tile early (overlaps compute)
      const int kt = (t + 1) * BKT;
#pragma unroll
      for (int s = 0; s < ASL; ++s)
        gload16(gA[s] + kt, sA + nxt * ASZ + (s * THREADS + tid) * 8);
#pragma unroll
      for (int s = 0; s < BSL; ++s)
        gload16(gB[s] + kt, sB + nxt * BSZ + (s * THREADS + tid) * 8);
    }
    const unsigned short* cA = sA + cur * ASZ;
    const unsigned short* cB = sB + cur * BSZ;
    bf16x8 af[2][MI], bfr[2][NJ];
#pragma unroll
    for (int i = 0; i < MI; i++) {
      af[0][i] = *reinterpret_cast<const bf16x8*>(&cA[(i * 16 + fr) * BKT + co0]);
      af[1][i] = *reinterpret_cast<const bf16x8*>(&cA[(i * 16 + fr) * BKT + co1]);
    }
#pragma unroll
    for (int j = 0; j < NJ; j++) {
      bfr[0][j] = *reinterpret_cast<const bf16x8*>(&cB[(wn * CW + j * 16 + fr) * BKT + co0]);
      bfr[1][j] = *reinterpret_cast<const bf16x8*>(&cB[(wn * CW + j * 16 + fr) * BKT + co1]);
    }
#pragma unroll
    for (int ks = 0; ks < 2; ks++)
#pragma unroll
      for (int i = 0; i < MI; i++)
#pragma unroll
        for (int j = 0; j < NJ; j++)
          acc[i][j] = __builtin_amdgcn_mfma_f32_16x16x32_bf16(af[ks][i], bfr[ks][j], acc[i][j], 0, 0, 0);
    __syncthreads();
  }

  const int fq = lane >> 4;
  const bool dorope = (MODE == 0) && (z < 2);
#pragma unroll
  for (int i = 0; i < MI; i++) {
#pragma unroll
    for (int j = 0; j < NJ; j++) {
#pragma unroll
      for (int r = 0; r < 4; r++) {
        const int row = m0 + i * 16 + fq * 4 + r;
        const int col = n0 + wn * CW + j * 16 + fr;
        float v = acc[i][j][r];
        if (MODE == 0) {
          const int l = row & 1023, d = col & 63;
          if (dorope) {
            // pair partner (d^1) lives in lane^1 (same i,j,r)
            const float other = __shfl_xor(v, 1);
            const int ti = (l << 5) + (d >> 1);
            const float c = ctab[ti], s = stab[ti];
            v = (d & 1) ? (other * s + v * c) : (v * c - other * s);
          }
          if (z == 0) v *= 0.125f;               // fold attn scale into Q
          // packed pair store: even-fr lane stores (own, partner) as u32
          const float vp = __shfl_xor(v, 1);
          if (!(fr & 1)) {
            const int b = row >> 10, h = col >> 6;
            const size_t idx = ((((size_t)b * NH + h) * LSEQ + l) << 6) + d;
            const unsigned int pk = (unsigned)f2h(v) | ((unsigned)f2h(vp) << 16);
            ((unsigned int*)C0)[((size_t)z * PLANE_ELEMS + idx) >> 1] = pk;
          }
        } else {
          ((float*)C0)[(size_t)row * N_GEMM + col] = v;
        }
      }
    }
  }
}

// ---------------- local windowed attention v5 (fp16 MFMA) -----------------
// Block = (bh, 64-query tile), XCD-swizzled grid. K span rows j=0..127 map to
// key l = lb-64+j (zero page for l<0 -> reference zero-pad softmax exactly).
// KF plane DMA'd via global_load_lds with pre-swizzled per-lane source.
// Q frags loaded directly as f16x8 (plane already scaled). P,V fp16.
__device__ __forceinline__ int kaddr(int j, int d) {   // Ks: 128 rows x 128B
  return j * 128 + ((((d >> 3) ^ (j & 7)) & 7) << 4) + ((d & 7) << 1);
}
__device__ __forceinline__ int taddr(int r, int c) {   // Vt/Ps: 64 rows x 256B
  return r * 256 + ((((c >> 3) ^ (r & 7)) & 15) << 4) + ((c & 7) << 1);
}

__global__ __launch_bounds__(256, 2) void local_attn5_k(
    const unsigned short* __restrict__ planes,
    const unsigned short* __restrict__ zp,
    unsigned short* __restrict__ O) {
  __shared__ __align__(16) unsigned char KsF[16384];
  __shared__ __align__(16) unsigned char VtB[16384];
  __shared__ __align__(16) unsigned char PsB[16384];

  const int tid = threadIdx.x;
  const int lane = tid & 63;
  const int wave = tid >> 6;
  const int lr = lane & 15;
  const int lg = lane >> 4;
  const int pb = blockIdx.x;
  const int lid = (pb & 7) * 64 + (pb >> 3);   // 512 = 8*64; bh-major per XCD
  const int bh = lid >> 4;
  const int lb = (lid & 15) << 6;

  const unsigned short* QFb = planes + ((size_t)bh << 16);
  const unsigned short* KFb = planes + (size_t)PLANE_ELEMS + ((size_t)bh << 16);
  const unsigned short* VFb = planes + 2 * (size_t)PLANE_ELEMS + ((size_t)bh << 16);

  // ---- K staging: pure DMA, source pre-swizzled to match kaddr ----
#pragma unroll
  for (int r = 0; r < 4; ++r) {
    const int item = r * 256 + tid;       // 0..1023
    const int j = item >> 3;              // 0..127
    const int c = item & 7;               // 16B chunk
    const int g = lb - 64 + j;
    const int sc = ((c ^ (j & 7)) << 3);  // swizzled source chunk (elements)
    const unsigned short* sK = (g >= 0) ? KFb + ((size_t)g << 6) + sc : zp + (c << 3);
    gload16(sK, KsF + item * 16);
  }

  // ---- V transpose staging from fp16 plane (bit-level pack, no math) ----
#pragma unroll
  for (int pp = 0; pp < 4; ++pp) {
    const int item = pp * 256 + tid;      // 0..1023
    const int jp = item >> 4;             // 0..63 (pair of j)
    const int d0 = (item & 15) << 2;      // 0..60
    const int g0 = lb - 64 + 2 * jp;
    ushort4 a = {0, 0, 0, 0}, b = {0, 0, 0, 0};
    if (g0 >= 0) a = *reinterpret_cast<const ushort4*>(VFb + ((size_t)g0 << 6) + d0);
    if (g0 + 1 >= 0) b = *reinterpret_cast<const ushort4*>(VFb + ((size_t)(g0 + 1) << 6) + d0);
    *reinterpret_cast<unsigned int*>(VtB + taddr(d0 + 0, 2 * jp)) = (unsigned)a.x | ((unsigned)b.x << 16);
    *reinterpret_cast<unsigned int*>(VtB + taddr(d0 + 1, 2 * jp)) = (unsigned)a.y | ((unsigned)b.y << 16);
    *reinterpret_cast<unsigned int*>(VtB + taddr(d0 + 2, 2 * jp)) = (unsigned)a.z | ((unsigned)b.z << 16);
    *reinterpret_cast<unsigned int*>(VtB + taddr(d0 + 3, 2 * jp)) = (unsigned)a.w | ((unsigned)b.w << 16);
  }
  __syncthreads();   // drains gload16 vmcnt + ds_writes

  // ---- Q fragments: direct f16x8 loads (plane already scaled by 0.125) ----
  const int rtbase = wave * 16;
  const size_t qoff = ((size_t)(lb + rtbase + lr) << 6);
  F16_8 qf[2];
#pragma unroll
  for (int ks = 0; ks < 2; ++ks)
    qf[ks].v = *reinterpret_cast<const f16x8*>(QFb + qoff + ks * 32 + lg * 8);

  // ---- scores: S[rt][j], wave owns rows rtbase..rtbase+15, all 128 j ----
  f32x4 acc[8] = {};
#pragma unroll
  for (int ks = 0; ks < 2; ++ks) {
    const int d0 = ks * 32 + lg * 8;
#pragma unroll
    for (int nt = 0; nt < 8; ++nt) {
      const int j = nt * 16 + lr;
      const f16x8 kf = *reinterpret_cast<const f16x8*>(KsF + kaddr(j, d0));
      acc[nt] = __builtin_amdgcn_mfma_f32_16x16x32_f16(qf[ks].v, kf, acc[nt], 0, 0, 0);
    }
  }

  // ---- masked softmax per row ----
  float sum4[4];
#pragma unroll
  for (int reg = 0; reg < 4; ++reg) {
    const int rt = rtbase + lg * 4 + reg;
    float m = -3.0e38f;
#pragma unroll
    for (int nt = 0; nt < 8; ++nt) {
      const int j = nt * 16 + lr;
      const bool valid = (j > rt) && (j <= rt + 64);
      const float sv = valid ? acc[nt][reg] : -3.0e38f;
      acc[nt][reg] = sv;
      m = fmaxf(m, sv);
    }
    m = fmaxf(m, __shfl_xor(m, 1));
    m = fmaxf(m, __shfl_xor(m, 2));
    m = fmaxf(m, __shfl_xor(m, 4));
    m = fmaxf(m, __shfl_xor(m, 8));
    float s = 0.f;
#pragma unroll
    for (int nt = 0; nt < 8; ++nt) {
      const float pv = (acc[nt][reg] > -1.0e37f) ? __expf(acc[nt][reg] - m) : 0.f;
      acc[nt][reg] = pv;
      s += pv;
    }
    s += __shfl_xor(s, 1);
    s += __shfl_xor(s, 2);
    s += __shfl_xor(s, 4);
    s += __shfl_xor(s, 8);
    sum4[reg] = s;
  }

  // ---- write P (fp16, swizzled; wave-private rows) ----
#pragma unroll
  for (int nt = 0; nt < 8; ++nt)
#pragma unroll
    for (int reg = 0; reg < 4; ++reg) {
      const int rt = rtbase + lg * 4 + reg;
      const int j = nt * 16 + lr;
      *reinterpret_cast<unsigned short*>(PsB + taddr(rt, j)) = f2h(acc[nt][reg]);
    }

  // ---- PV: out[rt][d] = sum_j P[rt][j] * V[j][d] ----
  f32x4 oacc[4] = {};
#pragma unroll
  for (int ks = 0; ks < 4; ++ks) {
    const int j0 = ks * 32 + lg * 8;
    const f16x8 pa = *reinterpret_cast<const f16x8*>(PsB + taddr(rtbase + lr, j0));
#pragma unroll
    for (int nt = 0; nt < 4; ++nt) {
      const int d = nt * 16 + lr;
      const f16x8 vf = *reinterpret_cast<const f16x8*>(VtB + taddr(d, j0));
      oacc[nt] = __builtin_amdgcn_mfma_f32_16x16x32_f16(pa, vf, oacc[nt], 0, 0, 0);
    }
  }

  // ---- normalize + write out (bf16, [b][l][h*64+d]) ----
  const int b = bh >> 4, h = bh & 15;
#pragma unroll
  for (int nt = 0; nt < 4; ++nt)
#pragma unroll
    for (int reg = 0; reg < 4; ++reg) {
      const int rt = rtbase + lg * 4 + reg;
      const int d = nt * 16 + lr;
      const float o = oacc[nt][reg] / sum4[reg];
      const int lq = lb + rt;
      O[(((size_t)b * LSEQ + lq) << 10) + (h << 6) + d] = f2bf(o);
    }
}

// ---------------- launch ----------------
extern "C" void kernel_launch(void* const* d_in, const int* in_sizes, int n_in,
                              void* d_out, int out_size, void* d_ws, size_t ws_size,
                              hipStream_t stream) {
  const float* x     = (const float*)d_in[0];
  const float* freqs = (const float*)d_in[1];
  const float* Wq    = (const float*)d_in[2];
  const float* Wk    = (const float*)d_in[3];
  const float* Wv    = (const float*)d_in[4];
  const float* Wo    = (const float*)d_in[5];
  float* out = (float*)d_out;
  char* ws = (char*)d_ws;

  // workspace layout (<= 28.8 MB)
  unsigned short* xb     = (unsigned short*)ws;                 // 4 MB: x bf16
  unsigned short* Wt     = (unsigned short*)(ws + (4u << 20));  // 8 MB: W^T bf16 x4
  unsigned short* planes = (unsigned short*)(ws + (12u << 20)); // 12 MB: QF KF VF (fp16)
  unsigned short* Oat    = (unsigned short*)(ws + (24u << 20)); // 4 MB: attn out bf16
  float* ctab = (float*)(ws + (28u << 20));                     // 128 KB
  float* stab = ctab + 32768;                                   // 128 KB
  unsigned short* zp = (unsigned short*)(ws + (28u << 20) + (1u << 19)); // 4 KB zeros

  prep_all_k<<<6273, 256, 0, stream>>>(x, xb, freqs, ctab, stab, Wq, Wk, Wv, Wo, Wt, zp);

  // Q,K,V = x @ {Wq,Wk,Wv}: RoPE fused, fp16 planes out, packed stores
  // R10-exact config (known best): 64x128, 1x8 waves, 768 blocks = 3/CU
  gemm_bf16_k<0, 64, 128, 8, 512><<<768, 512, 0, stream>>>(xb, Wt, planes, ctab, stab);

  // local attention (fp16 MFMA) -> bf16 [B*L][D_MODEL]
  local_attn5_k<<<512, 256, 0, stream>>>(planes, zp, Oat);

  // final projection -> fp32 d_out: 32x64 tiles, 1x4 waves -> 1024 blocks
  // = 4 blocks/CU = 16 waves/CU (was 8 -- occupancy is the proven lever here)
  gemm_bf16_k<1, 32, 64, 4, 256><<<1024, 256, 0, stream>>>(Oat, Wt + (3u << 20), out, ctab, stab);
}